// Round 7
// baseline (270.727 us; speedup 1.0000x reference)
//
#include <hip/hip_runtime.h>
#include <stdint.h>

#define NEG_SLOPE 0.01f
#define CHUNK 4096
#define CHUNK3 2048

typedef float f32x4 __attribute__((ext_vector_type(4)));
typedef short short8 __attribute__((ext_vector_type(8)));

struct RowsT { short8 b0, b1; ushort4 t0, t1, t2, t3; };

__device__ inline short f2bf(float f) {
    union { float f; uint32_t u; } x; x.f = f;
    uint32_t r = x.u + 0x7FFF + ((x.u >> 16) & 1);   // RNE
    return (short)(r >> 16);
}
__device__ inline float bf2f(unsigned short u) {
    union { uint32_t u; float f; } x; x.u = ((uint32_t)u) << 16; return x.f;
}

// ------- K_init_bf: counter init + ego fp32->bf16 + W^T frag pack (merged) --
__global__ void __launch_bounds__(256) k_init_bf(
        const float* __restrict__ ego, unsigned short* __restrict__ ego_bf,
        int NE8, int* head_cnt, int* type_cnt, int N,
        const float* __restrict__ rw, short* __restrict__ wfrag) {
    int i = blockIdx.x * 256 + threadIdx.x;
    if (i < N) head_cnt[i] = 0;
    if (i < 16) type_cnt[i] = 0;
    if (blockIdx.x < 16) {                 // W^T frag pack: blocks 0..15
        int r = blockIdx.x;
        int tid = threadIdx.x;
        int lane = tid & 63;
        int c = lane & 15, q = lane >> 4;
        for (int ph = 0; ph < 2; ++ph) {
            int pair = (tid >> 6) + ph * 4;
            int t4 = pair >> 1, kh = pair & 1;
            int m = t4 * 16 + c;
            short8 f;
            for (int j = 0; j < 8; ++j) {
                int k = kh * 32 + q * 8 + j;
                f[j] = f2bf(rw[r * 4096 + k * 64 + m]);
            }
            *(short8*)(wfrag + ((size_t)((r * 4 + t4) * 2 + kh) * 64 + lane) * 8) = f;
        }
    }
    if (i >= NE8) return;
    const float4* p = (const float4*)ego + (size_t)i * 2;
    float4 a = p[0], b = p[1];
    short8 v;
    v[0] = f2bf(a.x); v[1] = f2bf(a.y); v[2] = f2bf(a.z); v[3] = f2bf(a.w);
    v[4] = f2bf(b.x); v[5] = f2bf(b.y); v[6] = f2bf(b.z); v[7] = f2bf(b.w);
    *(short8*)(ego_bf + (size_t)i * 8) = v;
}

// ---------------- K1: histograms; head atomic's return value IS the rank ----
__global__ void __launch_bounds__(256) k1_hist(
        const int* __restrict__ head, const int* __restrict__ etype, int E,
        int* head_cnt, int* type_cnt, int* __restrict__ headrank) {
    __shared__ int lcnt[16];
    int t = threadIdx.x;
    if (t < 16) lcnt[t] = 0;
    __syncthreads();
    long long base = (long long)blockIdx.x * CHUNK;
    for (int i = t; i < CHUNK; i += 256) {
        long long e = base + i;
        if (e < E) {
            headrank[e] = atomicAdd(&head_cnt[head[e]], 1);   // coalesced write
            atomicAdd(&lcnt[etype[e]], 1);
        }
    }
    __syncthreads();
    if (t < 16 && lcnt[t]) atomicAdd(&type_cnt[t], lcnt[t]);
}

// ---------------- K2a: per-block partial sums of head_cnt ----------------
__global__ void __launch_bounds__(512) k2a(const int* __restrict__ head_cnt,
                                           int N, int* partial) {
    __shared__ int sw[8];
    int i = blockIdx.x * 512 + threadIdx.x;
    int v = (i < N) ? head_cnt[i] : 0;
    for (int off = 32; off; off >>= 1) v += __shfl_down(v, off);
    int w = threadIdx.x >> 6, lane = threadIdx.x & 63;
    if (lane == 0) sw[w] = v;
    __syncthreads();
    if (threadIdx.x == 0) {
        int s = 0;
        for (int j = 0; j < 8; ++j) s += sw[j];
        partial[blockIdx.x] = s;
    }
}

// ---------------- K2c: scan -> head_off; block 0 wave 7: type scan + pads ---
__global__ void __launch_bounds__(512) k2c(const int* __restrict__ head_cnt,
                                           int N, const int* __restrict__ partial,
                                           int* head_off, int E,
                                           const int* __restrict__ type_cnt,
                                           int* type_off_pad, int* type_fill,
                                           int4* __restrict__ recs) {
    __shared__ int s[512];
    __shared__ int bo_s;
    int t = threadIdx.x;
    if (t < 64) {
        int acc = 0;
        for (int i = t; i < blockIdx.x; i += 64) acc += partial[i];
        for (int off = 32; off; off >>= 1) acc += __shfl_down(acc, off);
        if (t == 0) bo_s = acc;
    }
    int i = blockIdx.x * 512 + t;
    int v = (i < N) ? head_cnt[i] : 0;
    s[t] = v;
    __syncthreads();
    for (int off = 1; off < 512; off <<= 1) {
        int x = (t >= off) ? s[t - off] : 0;
        __syncthreads();
        s[t] += x;
        __syncthreads();
    }
    if (i < N) head_off[i] = s[t] - v + bo_s;
    if (i == 0) head_off[N] = E;
    // type-bucket scan + pad-record fill (shuffle-only, one wave)
    if (blockIdx.x == 0 && t >= 448) {
        int lane = t & 63;
        int tv = (lane < 16) ? type_cnt[lane] : 0;
        int tp = (tv + 15) & ~15;
        int inc = tp;
        for (int off = 1; off < 16; off <<= 1) {
            int u = __shfl_up(inc, off);
            if (lane >= off) inc += u;
        }
        int excl = inc - tp;
        if (lane < 16) {
            type_off_pad[lane] = excl;
            type_fill[lane] = excl;
            if (lane == 15) type_off_pad[16] = inc;
        }
        for (int r = 0; r < 16; ++r) {
            int b = __shfl(excl, r) + __shfl(tv, r);
            int top1 = (r < 15) ? __shfl(excl, r + 1) : __shfl(inc, 15);
            int pads = top1 - b;
            if (lane < pads) {
                int4 pr; pr.x = 0; pr.y = 0; pr.z = -1; pr.w = r;
                recs[b + lane] = pr;
            }
        }
    }
}

// ------- K3: LDS-staged type scatter -> coalesced full-line record writes ---
__global__ void __launch_bounds__(256) k3_scatter(
        const int* __restrict__ etype, const int* __restrict__ head,
        const int* __restrict__ tail, const int* __restrict__ headrank, int E,
        const int* __restrict__ head_off, int* type_fill,
        int4* __restrict__ recs) {
    __shared__ int lcnt[16], lbase[16], loff[16];
    __shared__ int4 lrec[CHUNK3];
    int t = threadIdx.x;
    if (t < 16) lcnt[t] = 0;
    __syncthreads();
    long long base = (long long)blockIdx.x * CHUNK3;
    int myty[8], myrk[8];
    #pragma unroll
    for (int sIt = 0; sIt < 8; ++sIt) {
        long long e = base + t + sIt * 256;
        int ty = -1, rk = 0;
        if (e < E) { ty = etype[e]; rk = atomicAdd(&lcnt[ty], 1); }
        myty[sIt] = ty; myrk[sIt] = rk;
    }
    __syncthreads();
    if (t < 16) lbase[t] = atomicAdd(&type_fill[t], lcnt[t]);
    if (t >= 64 && t < 128) {              // one wave: exclusive scan of lcnt
        int lane = t - 64;
        int v = (lane < 16) ? lcnt[lane] : 0;
        int inc = v;
        for (int off = 1; off < 16; off <<= 1) {
            int u = __shfl_up(inc, off);
            if (lane >= off) inc += u;
        }
        if (lane < 16) loff[lane] = inc - v;
    }
    __syncthreads();
    #pragma unroll
    for (int sIt = 0; sIt < 8; ++sIt) {
        long long e = base + t + sIt * 256;
        if (e < E) {
            int h = head[e];
            int4 rec;
            rec.x = h;
            rec.y = tail[e];
            rec.z = head_off[h] + headrank[e];
            rec.w = myty[sIt];
            lrec[loff[myty[sIt]] + myrk[sIt]] = rec;
        }
    }
    __syncthreads();
    int nvalid = (int)(((long long)E - base < CHUNK3) ? ((long long)E - base) : CHUNK3);
    for (int i = t; i < nvalid; i += 256) {
        int4 rec = lrec[i];
        int r = rec.w;
        recs[lbase[r] + (i - loff[r])] = rec;    // coalesced by-type segments
    }
}

// ---------------- K4: scores via MFMA, DUAL-stream pipelined ----------------
__global__ void __launch_bounds__(256) k4_scores(
        const unsigned short* __restrict__ ego_bf, const short* __restrict__ wfrag,
        const int4* __restrict__ recs, const int* __restrict__ type_off_pad,
        int2* __restrict__ wt_sorted, int n_waves) {
    int wave = (blockIdx.x * blockDim.x + threadIdx.x) >> 6;
    int lane = threadIdx.x & 63;
    int c = lane & 15, q = lane >> 4;
    int G = type_off_pad[16] >> 4;
    int per = (G + n_waves - 1) / n_waves;
    int g0 = wave * per, g1 = min(G, g0 + per);
    if (g0 >= g1) return;

    int cur_r = -1;
    short8 wf[4][2];

    auto loadrec = [&](int g, int wdef) -> int4 {
        if (g < g1) return recs[((size_t)g << 4) + c];
        int4 p; p.x = 0; p.y = 0; p.z = -1; p.w = wdef;
        return p;
    };
    auto loadrows = [&](const int4& rec, RowsT& r) {
        const unsigned short* hr = ego_bf + (size_t)rec.x * 64;
        r.b0 = *(const short8*)(hr + q * 8);
        r.b1 = *(const short8*)(hr + 32 + q * 8);
        const unsigned short* tr = ego_bf + (size_t)rec.y * 64 + q * 4;
        r.t0 = *(const ushort4*)(tr);
        r.t1 = *(const ushort4*)(tr + 16);
        r.t2 = *(const ushort4*)(tr + 32);
        r.t3 = *(const ushort4*)(tr + 48);
    };
    auto compute = [&](const int4& rec, const RowsT& rw) {
        if (rec.w != cur_r) {                    // wave-uniform, rare
            cur_r = rec.w;
            const short* wp = wfrag + (size_t)cur_r * 4096;
            for (int t4 = 0; t4 < 4; ++t4)
                for (int kh = 0; kh < 2; ++kh)
                    wf[t4][kh] = *(const short8*)(wp + ((t4 * 2 + kh) * 64 + lane) * 8);
        }
        f32x4 acc[4];
        for (int t4 = 0; t4 < 4; ++t4) {
            f32x4 a = {0.f, 0.f, 0.f, 0.f};
            a = __builtin_amdgcn_mfma_f32_16x16x32_bf16(wf[t4][0], rw.b0, a, 0, 0, 0);
            a = __builtin_amdgcn_mfma_f32_16x16x32_bf16(wf[t4][1], rw.b1, a, 0, 0, 0);
            acc[t4] = a;
        }
        float d = acc[0][0] * bf2f(rw.t0.x) + acc[0][1] * bf2f(rw.t0.y)
                + acc[0][2] * bf2f(rw.t0.z) + acc[0][3] * bf2f(rw.t0.w)
                + acc[1][0] * bf2f(rw.t1.x) + acc[1][1] * bf2f(rw.t1.y)
                + acc[1][2] * bf2f(rw.t1.z) + acc[1][3] * bf2f(rw.t1.w)
                + acc[2][0] * bf2f(rw.t2.x) + acc[2][1] * bf2f(rw.t2.y)
                + acc[2][2] * bf2f(rw.t2.z) + acc[2][3] * bf2f(rw.t2.w)
                + acc[3][0] * bf2f(rw.t3.x) + acc[3][1] * bf2f(rw.t3.y)
                + acc[3][2] * bf2f(rw.t3.z) + acc[3][3] * bf2f(rw.t3.w);
        d += __shfl_xor(d, 16);
        d += __shfl_xor(d, 32);
        if (q == 0 && rec.z >= 0) {
            float s = d > 0.f ? d : NEG_SLOPE * d;
            int2 v;
            v.x = __float_as_int(__expf(s));
            v.y = rec.y;
            wt_sorted[rec.z] = v;                // plain 8B scatter, no atomic
        }
    };

    int gA = g0, gB = g0 + 1;
    int4 recA  = loadrec(gA, 0);
    int4 recB  = loadrec(gB, recA.w);
    int4 recA1 = loadrec(gA + 2, recA.w);
    int4 recB1 = loadrec(gB + 2, recB.w);
    RowsT rowsA, rowsB;
    loadrows(recA, rowsA);
    loadrows(recB, rowsB);
    while (gA < g1) {
        int4 recA2 = loadrec(gA + 4, recA1.w);
        int4 recB2 = loadrec(gB + 4, recB1.w);
        compute(recA, rowsA);
        RowsT rowsA1; loadrows(recA1, rowsA1);   // in flight across B-compute
        compute(recB, rowsB);
        RowsT rowsB1; loadrows(recB1, rowsB1);   // in flight across next A
        recA = recA1; recA1 = recA2; rowsA = rowsA1;
        recB = recB1; recB1 = recB2; rowsB = rowsB1;
        gA += 2; gB += 2;
    }
}

// ------- K5 v3: 8 lanes per head, no cross-lane reduction, deep MLP ---------
// Lane owns 8 output columns (c = (lane&7)*8 .. +8). All 8 lanes of a group
// see every edge of the head; den is computed redundantly. Window of 8
// (w,tail) pairs preloaded; 8 row-gathers issued back-to-back per window
// (128 lines in flight per wave). Output: 8 lanes x 32B = contiguous row.
__global__ void __launch_bounds__(256) k5_agg(
        const unsigned short* __restrict__ ego_bf,
        const int2* __restrict__ wt_sorted,
        const int* __restrict__ head_off, float* __restrict__ out,
        int N, int E) {
    int wave = (blockIdx.x * blockDim.x + threadIdx.x) >> 6;
    int lane = threadIdx.x & 63;
    int g = lane >> 3, lg = lane & 7;
    int h = wave * 8 + g;
    bool hv = h < N;
    int s0 = hv ? head_off[h] : 0;
    int s1 = hv ? head_off[h + 1] : 0;
    int cnt = s1 - s0;
    // wave-uniform loop bound: max cnt over the 8 groups (lane bits 3..5)
    int maxc = cnt;
    maxc = max(maxc, __shfl_xor(maxc, 8));
    maxc = max(maxc, __shfl_xor(maxc, 16));
    maxc = max(maxc, __shfl_xor(maxc, 32));
    float acc[8] = {0.f, 0.f, 0.f, 0.f, 0.f, 0.f, 0.f, 0.f};
    float den = 0.f;
    // window preload: lane lg holds edge s0+lg of its group (coalesced-ish)
    int2 wt = wt_sorted[min(s0 + lg, E - 1)];
    for (int jb = 0; jb < maxc; jb += 8) {
        int2 wtn = wt_sorted[min(s0 + jb + 8 + lg, E - 1)];  // next window, in flight
        int srcb = lane & 56;
        int tn_[8]; float w_[8];
        #pragma unroll
        for (int s = 0; s < 8; ++s) {
            tn_[s] = __shfl(wt.y, srcb + s);
            w_[s]  = __int_as_float(__shfl(wt.x, srcb + s));
        }
        short8 rows[8];
        #pragma unroll
        for (int s = 0; s < 8; ++s) {            // all 8 gathers issued together
            int tn = (jb + s < cnt) ? tn_[s] : 0;
            rows[s] = *(const short8*)(ego_bf + (size_t)tn * 64 + lg * 8);
        }
        #pragma unroll
        for (int s = 0; s < 8; ++s) {
            float we = (jb + s < cnt) ? w_[s] : 0.f;
            den += we;
            #pragma unroll
            for (int k = 0; k < 8; ++k)
                acc[k] += we * bf2f((unsigned short)rows[s][k]);
        }
        wt = wtn;
    }
    if (hv) {
        float sc = (cnt > 0) ? 1.f / (den * (float)cnt) : 0.f;
        float4 v0 = {acc[0] * sc, acc[1] * sc, acc[2] * sc, acc[3] * sc};
        float4 v1 = {acc[4] * sc, acc[5] * sc, acc[6] * sc, acc[7] * sc};
        float* op = out + (size_t)h * 64 + lg * 8;
        *(float4*)op = v0;
        *(float4*)(op + 4) = v1;
    }
}

extern "C" void kernel_launch(void* const* d_in, const int* in_sizes, int n_in,
                              void* d_out, int out_size, void* d_ws, size_t ws_size,
                              hipStream_t stream) {
    const float* ego = (const float*)d_in[0];
    const float* rw  = (const float*)d_in[1];
    const int* eidx  = (const int*)d_in[2];
    const int* etyp  = (const int*)d_in[3];
    int N = in_sizes[0] / 64;
    int E = in_sizes[3];
    const int* head = eidx;
    const int* tail = eidx + E;
    float* out = (float*)d_out;

    char* ws = (char*)d_ws;
    size_t o = 0;
    auto take = [&](size_t bytes) -> char* {
        char* p = ws + o;
        o = (o + bytes + 255) & ~(size_t)255;
        return p;
    };
    int PT  = E + 256;
    int nb2 = (N + 511) / 512;
    unsigned short* ego_bf = (unsigned short*)take((size_t)N * 64 * 2);
    short* wfrag      = (short*)take(16 * 4096 * 2);
    int2* wt_sorted   = (int2*)take((size_t)E * 8);
    int4* recs        = (int4*)take((size_t)PT * 16);
    int* headrank     = (int*)take((size_t)E * 4);
    int* head_cnt     = (int*)take((size_t)N * 4);
    int* head_off     = (int*)take((size_t)(N + 1) * 4);
    int* type_cnt     = (int*)take(64);
    int* type_off_pad = (int*)take(68);
    int* type_fill    = (int*)take(64);
    int* partial      = (int*)take((size_t)nb2 * 4);
    (void)ws_size; (void)n_in; (void)out_size;

    int NE8 = N * 64 / 8;
    k_init_bf<<<(NE8 + 255) / 256, 256, 0, stream>>>(ego, ego_bf, NE8,
                                                     head_cnt, type_cnt, N,
                                                     rw, wfrag);
    int nchunks = (E + CHUNK - 1) / CHUNK;
    k1_hist<<<nchunks, 256, 0, stream>>>(head, etyp, E, head_cnt, type_cnt, headrank);
    k2a<<<nb2, 512, 0, stream>>>(head_cnt, N, partial);
    k2c<<<nb2, 512, 0, stream>>>(head_cnt, N, partial, head_off, E,
                                 type_cnt, type_off_pad, type_fill, recs);
    int nchunks3 = (E + CHUNK3 - 1) / CHUNK3;
    k3_scatter<<<nchunks3, 256, 0, stream>>>(etyp, head, tail, headrank, E,
                                             head_off, type_fill, recs);

    int blocks4 = 2048;
    int n_waves = blocks4 * (256 / 64);
    k4_scores<<<blocks4, 256, 0, stream>>>(ego_bf, wfrag, recs, type_off_pad,
                                           wt_sorted, n_waves);

    k5_agg<<<(N + 31) / 32, 256, 0, stream>>>(ego_bf, wt_sorted, head_off, out,
                                              N, E);
}

// Round 9
// 266.828 us; speedup vs baseline: 1.0146x; 1.0146x over previous
//
#include <hip/hip_runtime.h>
#include <hip/hip_cooperative_groups.h>
#include <stdint.h>

namespace cg = cooperative_groups;

#define NEG_SLOPE 0.01f
#define GRID 768
#define BLK 256
#define NWAVES (GRID * BLK / 64)
#define LRECN 1664
#define CHUNK 4096
#define CHUNK3 2048

typedef float f32x4 __attribute__((ext_vector_type(4)));
typedef short short8 __attribute__((ext_vector_type(8)));

struct RowsT { short8 b0, b1; ushort4 t0, t1, t2, t3; };

struct Params {
    const float* ego; const float* rw;
    const int* head; const int* tail; const int* etype;
    unsigned short* ego_bf; short* wfrag;
    int2* wt_sorted; int4* recs;
    int* headrank; int* head_cnt; int* head_off;
    int* type_cnt; int* type_off_pad; int* type_fill; int* partial;
    float* out;
    int N, E, NE8, CH1, SL;
};

__device__ inline short f2bf(float f) {
    union { float f; uint32_t u; } x; x.f = f;
    uint32_t r = x.u + 0x7FFF + ((x.u >> 16) & 1);   // RNE
    return (short)(r >> 16);
}
__device__ inline float bf2f(unsigned short u) {
    union { uint32_t u; float f; } x; x.u = ((uint32_t)u) << 16; return x.f;
}

// ===================== cooperative mega-kernel =====================
// LDS: lrec 26.0 KB (aliased as scan buffer) + ~250 B -> ~26.3 KB/block.
// __launch_bounds__(256,3): 3 waves/EU floor -> VGPR<=168 -> 3 blocks/CU
// guaranteed; LDS allows 5/CU; GRID=768=3x256 is legal for cooperative.
__global__ void __launch_bounds__(BLK, 3) mega(Params p) {
    cg::grid_group grid = cg::this_grid();
    __shared__ int4 lrec[LRECN];
    __shared__ int lcnt[16], lbase[16], loff[16], sw[4];
    __shared__ int bo_s;
    int bid = blockIdx.x, t = threadIdx.x;
    int gtid = bid * BLK + t;
    int lane = t & 63;

    // ---- P0: counter init + ego fp32->bf16 + W^T frag pack ----
    for (int i = gtid; i < p.N; i += GRID * BLK) p.head_cnt[i] = 0;
    if (gtid < 16) p.type_cnt[gtid] = 0;
    for (int i = gtid; i < p.NE8; i += GRID * BLK) {
        const float4* q4 = (const float4*)p.ego + (size_t)i * 2;
        float4 a = q4[0], b = q4[1];
        short8 v;
        v[0] = f2bf(a.x); v[1] = f2bf(a.y); v[2] = f2bf(a.z); v[3] = f2bf(a.w);
        v[4] = f2bf(b.x); v[5] = f2bf(b.y); v[6] = f2bf(b.z); v[7] = f2bf(b.w);
        *(short8*)(p.ego_bf + (size_t)i * 8) = v;
    }
    if (bid < 16) {                      // A[m=t4*16+c][k=kh*32+q*8+j] = W[r][k][m]
        int r = bid;
        int c = lane & 15, q = lane >> 4;
        for (int ph = 0; ph < 2; ++ph) {
            int pair = (t >> 6) + ph * 4;
            int t4 = pair >> 1, kh = pair & 1;
            int m = t4 * 16 + c;
            short8 f;
            for (int j = 0; j < 8; ++j) {
                int k = kh * 32 + q * 8 + j;
                f[j] = f2bf(p.rw[r * 4096 + k * 64 + m]);
            }
            *(short8*)(p.wfrag + ((size_t)((r * 4 + t4) * 2 + kh) * 64 + lane) * 8) = f;
        }
    }
    grid.sync();

    // ---- P1: histograms; head atomic's return value IS the rank ----
    if (t < 16) lcnt[t] = 0;
    __syncthreads();
    {
        long long base = (long long)bid * p.CH1;
        for (int i = t; i < p.CH1; i += BLK) {
            long long e = base + i;
            if (e < p.E) {
                p.headrank[e] = atomicAdd(&p.head_cnt[p.head[e]], 1);
                atomicAdd(&lcnt[p.etype[e]], 1);
            }
        }
    }
    __syncthreads();
    if (t < 16 && lcnt[t]) atomicAdd(&p.type_cnt[t], lcnt[t]);
    grid.sync();

    // ---- P2a: per-block slice sums of head_cnt ----
    {
        int idx = bid * p.SL + t;
        int v = (t < p.SL && idx < p.N) ? p.head_cnt[idx] : 0;
        for (int off = 32; off; off >>= 1) v += __shfl_down(v, off);
        if (lane == 0) sw[t >> 6] = v;
        __syncthreads();
        if (t == 0) p.partial[bid] = sw[0] + sw[1] + sw[2] + sw[3];
    }
    grid.sync();

    // ---- P2b: head_off scan (256-wide); then block 0: type scan + pads ----
    {
        int* s2 = (int*)lrec;            // alias (phase-disjoint with P4)
        if (t < 64) {
            int acc = 0;
            for (int i = t; i < bid; i += 64) acc += p.partial[i];
            for (int off = 32; off; off >>= 1) acc += __shfl_down(acc, off);
            if (t == 0) bo_s = acc;
        }
        int idx = bid * p.SL + t;        // SL <= 256 required
        int v = (t < p.SL && idx < p.N) ? p.head_cnt[idx] : 0;
        s2[t] = v;
        __syncthreads();
        for (int off = 1; off < 256; off <<= 1) {
            int x = (t >= off) ? s2[t - off] : 0;
            __syncthreads();
            s2[t] += x;
            __syncthreads();
        }
        if (t < p.SL && idx < p.N) p.head_off[idx] = s2[t] - v + bo_s;
        if (bid == 0 && t == 0) p.head_off[p.N] = p.E;
        __syncthreads();
        if (bid == 0 && t < 64) {        // shuffle-only, one wave
            int tv = (lane < 16) ? p.type_cnt[lane] : 0;
            int tp = (tv + 15) & ~15;
            int inc = tp;
            for (int off = 1; off < 16; off <<= 1) {
                int u = __shfl_up(inc, off);
                if (lane >= off) inc += u;
            }
            int excl = inc - tp;
            if (lane < 16) {
                p.type_off_pad[lane] = excl;
                p.type_fill[lane] = excl;
                if (lane == 15) p.type_off_pad[16] = inc;
            }
            int tot = __shfl(inc, 15);
            for (int r = 0; r < 16; ++r) {
                int b = __shfl(excl, r) + __shfl(tv, r);
                int top1 = (r < 15) ? __shfl(excl, r + 1) : tot;
                int pads = top1 - b;
                if (lane < pads) {
                    int4 pr; pr.x = 0; pr.y = 0; pr.z = -1; pr.w = r;
                    p.recs[b + lane] = pr;
                }
            }
        }
    }
    grid.sync();

    // ---- P4: LDS-staged type scatter -> coalesced record writes ----
    {
        if (t < 16) lcnt[t] = 0;
        __syncthreads();
        long long base = (long long)bid * p.CH1;
        long long end = base + p.CH1; if (end > p.E) end = p.E;
        int myty[8], myrk[8];
        #pragma unroll
        for (int sIt = 0; sIt < 8; ++sIt) {
            int ofs = t + sIt * BLK;
            long long e = base + ofs;
            int ty = -1, rk = 0;
            if (ofs < p.CH1 && e < p.E) { ty = p.etype[e]; rk = atomicAdd(&lcnt[ty], 1); }
            myty[sIt] = ty; myrk[sIt] = rk;
        }
        __syncthreads();
        if (t < 16) lbase[t] = atomicAdd(&p.type_fill[t], lcnt[t]);
        if (t >= 64 && t < 128) {        // one wave: exclusive scan of lcnt
            int v = (lane < 16) ? lcnt[lane] : 0;
            int inc = v;
            for (int off = 1; off < 16; off <<= 1) {
                int u = __shfl_up(inc, off);
                if (lane >= off) inc += u;
            }
            if (lane < 16) loff[lane] = inc - v;
        }
        __syncthreads();
        #pragma unroll
        for (int sIt = 0; sIt < 8; ++sIt) {
            int ofs = t + sIt * BLK;
            long long e = base + ofs;
            if (myty[sIt] >= 0) {
                int h = p.head[e];
                int4 rec;
                rec.x = h;
                rec.y = p.tail[e];
                rec.z = p.head_off[h] + p.headrank[e];
                rec.w = myty[sIt];
                lrec[loff[myty[sIt]] + myrk[sIt]] = rec;
            }
        }
        __syncthreads();
        int nv = (int)(end - base); if (nv < 0) nv = 0;
        for (int i = t; i < nv; i += BLK) {
            int4 rec = lrec[i];
            int r = rec.w;
            p.recs[lbase[r] + (i - loff[r])] = rec;
        }
    }
    grid.sync();

    // ---- P5: MFMA scores, dual-stream pipelined ----
    {
        int wave = gtid >> 6;
        int c = lane & 15, q = lane >> 4;
        int G = p.type_off_pad[16] >> 4;
        int per = (G + NWAVES - 1) / NWAVES;
        int g0 = wave * per, g1 = min(G, g0 + per);
        if (g0 < g1) {
            int cur_r = -1;
            short8 wf[4][2];
            auto loadrec = [&](int g, int wdef) -> int4 {
                if (g < g1) return p.recs[((size_t)g << 4) + c];
                int4 pr; pr.x = 0; pr.y = 0; pr.z = -1; pr.w = wdef;
                return pr;
            };
            auto loadrows = [&](const int4& rec, RowsT& r) {
                const unsigned short* hr = p.ego_bf + (size_t)rec.x * 64;
                r.b0 = *(const short8*)(hr + q * 8);
                r.b1 = *(const short8*)(hr + 32 + q * 8);
                const unsigned short* tr = p.ego_bf + (size_t)rec.y * 64 + q * 4;
                r.t0 = *(const ushort4*)(tr);
                r.t1 = *(const ushort4*)(tr + 16);
                r.t2 = *(const ushort4*)(tr + 32);
                r.t3 = *(const ushort4*)(tr + 48);
            };
            auto compute = [&](const int4& rec, const RowsT& rw) {
                if (rec.w != cur_r) {            // wave-uniform, rare
                    cur_r = rec.w;
                    const short* wp = p.wfrag + (size_t)cur_r * 4096;
                    for (int t4 = 0; t4 < 4; ++t4)
                        for (int kh = 0; kh < 2; ++kh)
                            wf[t4][kh] = *(const short8*)(wp + ((t4 * 2 + kh) * 64 + lane) * 8);
                }
                f32x4 acc[4];
                for (int t4 = 0; t4 < 4; ++t4) {
                    f32x4 a = {0.f, 0.f, 0.f, 0.f};
                    a = __builtin_amdgcn_mfma_f32_16x16x32_bf16(wf[t4][0], rw.b0, a, 0, 0, 0);
                    a = __builtin_amdgcn_mfma_f32_16x16x32_bf16(wf[t4][1], rw.b1, a, 0, 0, 0);
                    acc[t4] = a;
                }
                float d = acc[0][0] * bf2f(rw.t0.x) + acc[0][1] * bf2f(rw.t0.y)
                        + acc[0][2] * bf2f(rw.t0.z) + acc[0][3] * bf2f(rw.t0.w)
                        + acc[1][0] * bf2f(rw.t1.x) + acc[1][1] * bf2f(rw.t1.y)
                        + acc[1][2] * bf2f(rw.t1.z) + acc[1][3] * bf2f(rw.t1.w)
                        + acc[2][0] * bf2f(rw.t2.x) + acc[2][1] * bf2f(rw.t2.y)
                        + acc[2][2] * bf2f(rw.t2.z) + acc[2][3] * bf2f(rw.t2.w)
                        + acc[3][0] * bf2f(rw.t3.x) + acc[3][1] * bf2f(rw.t3.y)
                        + acc[3][2] * bf2f(rw.t3.z) + acc[3][3] * bf2f(rw.t3.w);
                d += __shfl_xor(d, 16);
                d += __shfl_xor(d, 32);
                if (q == 0 && rec.z >= 0) {
                    float s = d > 0.f ? d : NEG_SLOPE * d;
                    int2 v;
                    v.x = __float_as_int(__expf(s));
                    v.y = rec.y;
                    p.wt_sorted[rec.z] = v;      // plain 8B scatter, no atomic
                }
            };
            int gA = g0, gB = g0 + 1;
            int4 recA  = loadrec(gA, 0);
            int4 recB  = loadrec(gB, recA.w);
            int4 recA1 = loadrec(gA + 2, recA.w);
            int4 recB1 = loadrec(gB + 2, recB.w);
            RowsT rowsA, rowsB;
            loadrows(recA, rowsA);
            loadrows(recB, rowsB);
            while (gA < g1) {
                int4 recA2 = loadrec(gA + 4, recA1.w);
                int4 recB2 = loadrec(gB + 4, recB1.w);
                compute(recA, rowsA);
                RowsT rowsA1; loadrows(recA1, rowsA1);
                compute(recB, rowsB);
                RowsT rowsB1; loadrows(recB1, rowsB1);
                recA = recA1; recA1 = recA2; rowsA = rowsA1;
                recB = recB1; recB1 = recB2; rowsB = rowsB1;
                gA += 2; gB += 2;
            }
        }
    }
    grid.sync();

    // ---- P6: per-head aggregation, 8 lanes/head, grid-stride jobs ----
    {
        int wv = gtid >> 6;
        int g = lane >> 3, lg = lane & 7;
        int njobs = (p.N + 7) >> 3;
        for (int job = wv; job < njobs; job += NWAVES) {
            int h = job * 8 + g;
            bool hv = h < p.N;
            int s0 = hv ? p.head_off[h] : 0;
            int s1 = hv ? p.head_off[h + 1] : 0;
            int cnt = s1 - s0;
            int maxc = cnt;
            maxc = max(maxc, __shfl_xor(maxc, 8));
            maxc = max(maxc, __shfl_xor(maxc, 16));
            maxc = max(maxc, __shfl_xor(maxc, 32));
            float acc[8] = {0.f, 0.f, 0.f, 0.f, 0.f, 0.f, 0.f, 0.f};
            float den = 0.f;
            int2 wt = p.wt_sorted[min(s0 + lg, p.E - 1)];
            for (int jb = 0; jb < maxc; jb += 8) {
                int2 wtn = p.wt_sorted[min(s0 + jb + 8 + lg, p.E - 1)];
                int srcb = lane & 56;
                int tn_[8]; float w_[8];
                #pragma unroll
                for (int s = 0; s < 8; ++s) {
                    tn_[s] = __shfl(wt.y, srcb + s);
                    w_[s]  = __int_as_float(__shfl(wt.x, srcb + s));
                }
                short8 rows[8];
                #pragma unroll
                for (int s = 0; s < 8; ++s) {
                    int tn = (jb + s < cnt) ? tn_[s] : 0;
                    rows[s] = *(const short8*)(p.ego_bf + (size_t)tn * 64 + lg * 8);
                }
                #pragma unroll
                for (int s = 0; s < 8; ++s) {
                    float we = (jb + s < cnt) ? w_[s] : 0.f;
                    den += we;
                    #pragma unroll
                    for (int k = 0; k < 8; ++k)
                        acc[k] += we * bf2f((unsigned short)rows[s][k]);
                }
                wt = wtn;
            }
            if (hv) {
                float sc = (cnt > 0) ? 1.f / (den * (float)cnt) : 0.f;
                float4 v0 = {acc[0] * sc, acc[1] * sc, acc[2] * sc, acc[3] * sc};
                float4 v1 = {acc[4] * sc, acc[5] * sc, acc[6] * sc, acc[7] * sc};
                float* op = p.out + (size_t)h * 64 + lg * 8;
                *(float4*)op = v0;
                *(float4*)(op + 4) = v1;
            }
        }
    }
}

// ===================== fallback path (round-7, proven) =====================
__global__ void __launch_bounds__(256) k_init_bf(
        const float* __restrict__ ego, unsigned short* __restrict__ ego_bf,
        int NE8, int* head_cnt, int* type_cnt, int N,
        const float* __restrict__ rw, short* __restrict__ wfrag) {
    int i = blockIdx.x * 256 + threadIdx.x;
    if (i < N) head_cnt[i] = 0;
    if (i < 16) type_cnt[i] = 0;
    if (blockIdx.x < 16) {
        int r = blockIdx.x;
        int tid = threadIdx.x;
        int lane = tid & 63;
        int c = lane & 15, q = lane >> 4;
        for (int ph = 0; ph < 2; ++ph) {
            int pair = (tid >> 6) + ph * 4;
            int t4 = pair >> 1, kh = pair & 1;
            int m = t4 * 16 + c;
            short8 f;
            for (int j = 0; j < 8; ++j) {
                int k = kh * 32 + q * 8 + j;
                f[j] = f2bf(rw[r * 4096 + k * 64 + m]);
            }
            *(short8*)(wfrag + ((size_t)((r * 4 + t4) * 2 + kh) * 64 + lane) * 8) = f;
        }
    }
    if (i >= NE8) return;
    const float4* p = (const float4*)ego + (size_t)i * 2;
    float4 a = p[0], b = p[1];
    short8 v;
    v[0] = f2bf(a.x); v[1] = f2bf(a.y); v[2] = f2bf(a.z); v[3] = f2bf(a.w);
    v[4] = f2bf(b.x); v[5] = f2bf(b.y); v[6] = f2bf(b.z); v[7] = f2bf(b.w);
    *(short8*)(ego_bf + (size_t)i * 8) = v;
}

__global__ void __launch_bounds__(256) k1_hist(
        const int* __restrict__ head, const int* __restrict__ etype, int E,
        int* head_cnt, int* type_cnt, int* __restrict__ headrank) {
    __shared__ int lcnt[16];
    int t = threadIdx.x;
    if (t < 16) lcnt[t] = 0;
    __syncthreads();
    long long base = (long long)blockIdx.x * CHUNK;
    for (int i = t; i < CHUNK; i += 256) {
        long long e = base + i;
        if (e < E) {
            headrank[e] = atomicAdd(&head_cnt[head[e]], 1);
            atomicAdd(&lcnt[etype[e]], 1);
        }
    }
    __syncthreads();
    if (t < 16 && lcnt[t]) atomicAdd(&type_cnt[t], lcnt[t]);
}

__global__ void __launch_bounds__(512) k2a(const int* __restrict__ head_cnt,
                                           int N, int* partial) {
    __shared__ int sw[8];
    int i = blockIdx.x * 512 + threadIdx.x;
    int v = (i < N) ? head_cnt[i] : 0;
    for (int off = 32; off; off >>= 1) v += __shfl_down(v, off);
    int w = threadIdx.x >> 6, lane = threadIdx.x & 63;
    if (lane == 0) sw[w] = v;
    __syncthreads();
    if (threadIdx.x == 0) {
        int s = 0;
        for (int j = 0; j < 8; ++j) s += sw[j];
        partial[blockIdx.x] = s;
    }
}

__global__ void __launch_bounds__(512) k2c(const int* __restrict__ head_cnt,
                                           int N, const int* __restrict__ partial,
                                           int* head_off, int E,
                                           const int* __restrict__ type_cnt,
                                           int* type_off_pad, int* type_fill,
                                           int4* __restrict__ recs) {
    __shared__ int s[512];
    __shared__ int bo_s;
    int t = threadIdx.x;
    if (t < 64) {
        int acc = 0;
        for (int i = t; i < blockIdx.x; i += 64) acc += partial[i];
        for (int off = 32; off; off >>= 1) acc += __shfl_down(acc, off);
        if (t == 0) bo_s = acc;
    }
    int i = blockIdx.x * 512 + t;
    int v = (i < N) ? head_cnt[i] : 0;
    s[t] = v;
    __syncthreads();
    for (int off = 1; off < 512; off <<= 1) {
        int x = (t >= off) ? s[t - off] : 0;
        __syncthreads();
        s[t] += x;
        __syncthreads();
    }
    if (i < N) head_off[i] = s[t] - v + bo_s;
    if (i == 0) head_off[N] = E;
    if (blockIdx.x == 0 && t >= 448) {
        int lane = t & 63;
        int tv = (lane < 16) ? type_cnt[lane] : 0;
        int tp = (tv + 15) & ~15;
        int inc = tp;
        for (int off = 1; off < 16; off <<= 1) {
            int u = __shfl_up(inc, off);
            if (lane >= off) inc += u;
        }
        int excl = inc - tp;
        if (lane < 16) {
            type_off_pad[lane] = excl;
            type_fill[lane] = excl;
            if (lane == 15) type_off_pad[16] = inc;
        }
        int tot = __shfl(inc, 15);
        for (int r = 0; r < 16; ++r) {
            int b = __shfl(excl, r) + __shfl(tv, r);
            int top1 = (r < 15) ? __shfl(excl, r + 1) : tot;
            int pads = top1 - b;
            if (lane < pads) {
                int4 pr; pr.x = 0; pr.y = 0; pr.z = -1; pr.w = r;
                recs[b + lane] = pr;
            }
        }
    }
}

__global__ void __launch_bounds__(256) k3_scatter(
        const int* __restrict__ etype, const int* __restrict__ head,
        const int* __restrict__ tail, const int* __restrict__ headrank, int E,
        const int* __restrict__ head_off, int* type_fill,
        int4* __restrict__ recs) {
    __shared__ int lcnt[16], lbase[16], loff[16];
    __shared__ int4 lrec[CHUNK3];
    int t = threadIdx.x;
    int lane = t & 63;
    if (t < 16) lcnt[t] = 0;
    __syncthreads();
    long long base = (long long)blockIdx.x * CHUNK3;
    int myty[8], myrk[8];
    #pragma unroll
    for (int sIt = 0; sIt < 8; ++sIt) {
        long long e = base + t + sIt * 256;
        int ty = -1, rk = 0;
        if (e < E) { ty = etype[e]; rk = atomicAdd(&lcnt[ty], 1); }
        myty[sIt] = ty; myrk[sIt] = rk;
    }
    __syncthreads();
    if (t < 16) lbase[t] = atomicAdd(&type_fill[t], lcnt[t]);
    if (t >= 64 && t < 128) {
        int v = (lane < 16) ? lcnt[lane] : 0;
        int inc = v;
        for (int off = 1; off < 16; off <<= 1) {
            int u = __shfl_up(inc, off);
            if (lane >= off) inc += u;
        }
        if (lane < 16) loff[lane] = inc - v;
    }
    __syncthreads();
    #pragma unroll
    for (int sIt = 0; sIt < 8; ++sIt) {
        long long e = base + t + sIt * 256;
        if (myty[sIt] >= 0) {
            int h = head[e];
            int4 rec;
            rec.x = h;
            rec.y = tail[e];
            rec.z = head_off[h] + headrank[e];
            rec.w = myty[sIt];
            lrec[loff[myty[sIt]] + myrk[sIt]] = rec;
        }
    }
    __syncthreads();
    int nv = (int)(((long long)E - base < CHUNK3) ? ((long long)E - base) : CHUNK3);
    for (int i = t; i < nv; i += 256) {
        int4 rec = lrec[i];
        int r = rec.w;
        recs[lbase[r] + (i - loff[r])] = rec;
    }
}

__global__ void __launch_bounds__(256) k4_scores(
        const unsigned short* __restrict__ ego_bf, const short* __restrict__ wfrag,
        const int4* __restrict__ recs, const int* __restrict__ type_off_pad,
        int2* __restrict__ wt_sorted, int n_waves) {
    int wave = (blockIdx.x * blockDim.x + threadIdx.x) >> 6;
    int lane = threadIdx.x & 63;
    int c = lane & 15, q = lane >> 4;
    int G = type_off_pad[16] >> 4;
    int per = (G + n_waves - 1) / n_waves;
    int g0 = wave * per, g1 = min(G, g0 + per);
    if (g0 >= g1) return;
    int cur_r = -1;
    short8 wf[4][2];
    auto loadrec = [&](int g, int wdef) -> int4 {
        if (g < g1) return recs[((size_t)g << 4) + c];
        int4 p; p.x = 0; p.y = 0; p.z = -1; p.w = wdef;
        return p;
    };
    auto loadrows = [&](const int4& rec, RowsT& r) {
        const unsigned short* hr = ego_bf + (size_t)rec.x * 64;
        r.b0 = *(const short8*)(hr + q * 8);
        r.b1 = *(const short8*)(hr + 32 + q * 8);
        const unsigned short* tr = ego_bf + (size_t)rec.y * 64 + q * 4;
        r.t0 = *(const ushort4*)(tr);
        r.t1 = *(const ushort4*)(tr + 16);
        r.t2 = *(const ushort4*)(tr + 32);
        r.t3 = *(const ushort4*)(tr + 48);
    };
    auto compute = [&](const int4& rec, const RowsT& rw) {
        if (rec.w != cur_r) {
            cur_r = rec.w;
            const short* wp = wfrag + (size_t)cur_r * 4096;
            for (int t4 = 0; t4 < 4; ++t4)
                for (int kh = 0; kh < 2; ++kh)
                    wf[t4][kh] = *(const short8*)(wp + ((t4 * 2 + kh) * 64 + lane) * 8);
        }
        f32x4 acc[4];
        for (int t4 = 0; t4 < 4; ++t4) {
            f32x4 a = {0.f, 0.f, 0.f, 0.f};
            a = __builtin_amdgcn_mfma_f32_16x16x32_bf16(wf[t4][0], rw.b0, a, 0, 0, 0);
            a = __builtin_amdgcn_mfma_f32_16x16x32_bf16(wf[t4][1], rw.b1, a, 0, 0, 0);
            acc[t4] = a;
        }
        float d = acc[0][0] * bf2f(rw.t0.x) + acc[0][1] * bf2f(rw.t0.y)
                + acc[0][2] * bf2f(rw.t0.z) + acc[0][3] * bf2f(rw.t0.w)
                + acc[1][0] * bf2f(rw.t1.x) + acc[1][1] * bf2f(rw.t1.y)
                + acc[1][2] * bf2f(rw.t1.z) + acc[1][3] * bf2f(rw.t1.w)
                + acc[2][0] * bf2f(rw.t2.x) + acc[2][1] * bf2f(rw.t2.y)
                + acc[2][2] * bf2f(rw.t2.z) + acc[2][3] * bf2f(rw.t2.w)
                + acc[3][0] * bf2f(rw.t3.x) + acc[3][1] * bf2f(rw.t3.y)
                + acc[3][2] * bf2f(rw.t3.z) + acc[3][3] * bf2f(rw.t3.w);
        d += __shfl_xor(d, 16);
        d += __shfl_xor(d, 32);
        if (q == 0 && rec.z >= 0) {
            float s = d > 0.f ? d : NEG_SLOPE * d;
            int2 v;
            v.x = __float_as_int(__expf(s));
            v.y = rec.y;
            wt_sorted[rec.z] = v;
        }
    };
    int gA = g0, gB = g0 + 1;
    int4 recA  = loadrec(gA, 0);
    int4 recB  = loadrec(gB, recA.w);
    int4 recA1 = loadrec(gA + 2, recA.w);
    int4 recB1 = loadrec(gB + 2, recB.w);
    RowsT rowsA, rowsB;
    loadrows(recA, rowsA);
    loadrows(recB, rowsB);
    while (gA < g1) {
        int4 recA2 = loadrec(gA + 4, recA1.w);
        int4 recB2 = loadrec(gB + 4, recB1.w);
        compute(recA, rowsA);
        RowsT rowsA1; loadrows(recA1, rowsA1);
        compute(recB, rowsB);
        RowsT rowsB1; loadrows(recB1, rowsB1);
        recA = recA1; recA1 = recA2; rowsA = rowsA1;
        recB = recB1; recB1 = recB2; rowsB = rowsB1;
        gA += 2; gB += 2;
    }
}

__global__ void __launch_bounds__(256) k5_agg(
        const unsigned short* __restrict__ ego_bf,
        const int2* __restrict__ wt_sorted,
        const int* __restrict__ head_off, float* __restrict__ out,
        int N, int E) {
    int wave = (blockIdx.x * blockDim.x + threadIdx.x) >> 6;
    int lane = threadIdx.x & 63;
    int g = lane >> 3, lg = lane & 7;
    int h = wave * 8 + g;
    bool hv = h < N;
    int s0 = hv ? head_off[h] : 0;
    int s1 = hv ? head_off[h + 1] : 0;
    int cnt = s1 - s0;
    int maxc = cnt;
    maxc = max(maxc, __shfl_xor(maxc, 8));
    maxc = max(maxc, __shfl_xor(maxc, 16));
    maxc = max(maxc, __shfl_xor(maxc, 32));
    float acc[8] = {0.f, 0.f, 0.f, 0.f, 0.f, 0.f, 0.f, 0.f};
    float den = 0.f;
    int2 wt = wt_sorted[min(s0 + lg, E - 1)];
    for (int jb = 0; jb < maxc; jb += 8) {
        int2 wtn = wt_sorted[min(s0 + jb + 8 + lg, E - 1)];
        int srcb = lane & 56;
        int tn_[8]; float w_[8];
        #pragma unroll
        for (int s = 0; s < 8; ++s) {
            tn_[s] = __shfl(wt.y, srcb + s);
            w_[s]  = __int_as_float(__shfl(wt.x, srcb + s));
        }
        short8 rows[8];
        #pragma unroll
        for (int s = 0; s < 8; ++s) {
            int tn = (jb + s < cnt) ? tn_[s] : 0;
            rows[s] = *(const short8*)(ego_bf + (size_t)tn * 64 + lg * 8);
        }
        #pragma unroll
        for (int s = 0; s < 8; ++s) {
            float we = (jb + s < cnt) ? w_[s] : 0.f;
            den += we;
            #pragma unroll
            for (int k = 0; k < 8; ++k)
                acc[k] += we * bf2f((unsigned short)rows[s][k]);
        }
        wt = wtn;
    }
    if (hv) {
        float sc = (cnt > 0) ? 1.f / (den * (float)cnt) : 0.f;
        float4 v0 = {acc[0] * sc, acc[1] * sc, acc[2] * sc, acc[3] * sc};
        float4 v1 = {acc[4] * sc, acc[5] * sc, acc[6] * sc, acc[7] * sc};
        float* op = out + (size_t)h * 64 + lg * 8;
        *(float4*)op = v0;
        *(float4*)(op + 4) = v1;
    }
}

extern "C" void kernel_launch(void* const* d_in, const int* in_sizes, int n_in,
                              void* d_out, int out_size, void* d_ws, size_t ws_size,
                              hipStream_t stream) {
    const float* ego = (const float*)d_in[0];
    const float* rw  = (const float*)d_in[1];
    const int* eidx  = (const int*)d_in[2];
    const int* etyp  = (const int*)d_in[3];
    int N = in_sizes[0] / 64;
    int E = in_sizes[3];
    const int* head = eidx;
    const int* tail = eidx + E;

    char* ws = (char*)d_ws;
    size_t o = 0;
    auto take = [&](size_t bytes) -> char* {
        char* p = ws + o;
        o = (o + bytes + 255) & ~(size_t)255;
        return p;
    };
    int PT = E + 256;
    int nb2 = (N + 511) / 512;
    int npart = (nb2 > GRID ? nb2 : GRID) + 4;
    Params pm;
    pm.ego_bf       = (unsigned short*)take((size_t)N * 64 * 2);
    pm.wfrag        = (short*)take(16 * 4096 * 2);
    pm.wt_sorted    = (int2*)take((size_t)E * 8);
    pm.recs         = (int4*)take((size_t)PT * 16);
    pm.headrank     = (int*)take((size_t)E * 4);
    pm.head_cnt     = (int*)take((size_t)N * 4);
    pm.head_off     = (int*)take((size_t)(N + 1) * 4);
    pm.type_cnt     = (int*)take(64);
    pm.type_off_pad = (int*)take(68);
    pm.type_fill    = (int*)take(64);
    pm.partial      = (int*)take((size_t)npart * 4);
    (void)ws_size; (void)n_in; (void)out_size;

    pm.ego = ego; pm.rw = rw;
    pm.head = head; pm.tail = tail; pm.etype = etyp;
    pm.out = (float*)d_out;
    pm.N = N; pm.E = E;
    pm.NE8 = N * 8;
    pm.CH1 = (E + GRID - 1) / GRID;      // 1628 for E=1.25M; must be <= LRECN
    pm.SL  = (N + GRID - 1) / GRID;      // 131 for N=100k; must be <= 256

    bool coop = false;
    if (pm.CH1 <= LRECN && pm.SL <= 256) {
        int nb = 0;
        hipError_t oe = hipOccupancyMaxActiveBlocksPerMultiprocessor(
            &nb, (const void*)mega, BLK, 0);
        if (oe == hipSuccess && nb >= 3) {
            void* args[] = { &pm };
            hipError_t le = hipLaunchCooperativeKernel(
                (void*)mega, dim3(GRID), dim3(BLK), args, 0, stream);
            coop = (le == hipSuccess);
        }
    }
    if (!coop) {
        int NE8 = N * 8;
        k_init_bf<<<(NE8 * 1 + 255) / 256, 256, 0, stream>>>(ego, pm.ego_bf, NE8,
                pm.head_cnt, pm.type_cnt, N, rw, pm.wfrag);
        int nchunks = (E + CHUNK - 1) / CHUNK;
        k1_hist<<<nchunks, 256, 0, stream>>>(head, etyp, E, pm.head_cnt,
                pm.type_cnt, pm.headrank);
        k2a<<<nb2, 512, 0, stream>>>(pm.head_cnt, N, pm.partial);
        k2c<<<nb2, 512, 0, stream>>>(pm.head_cnt, N, pm.partial, pm.head_off, E,
                pm.type_cnt, pm.type_off_pad, pm.type_fill, pm.recs);
        int nchunks3 = (E + CHUNK3 - 1) / CHUNK3;
        k3_scatter<<<nchunks3, 256, 0, stream>>>(etyp, head, tail, pm.headrank, E,
                pm.head_off, pm.type_fill, pm.recs);
        int blocks4 = 2048;
        int n_waves = blocks4 * (256 / 64);
        k4_scores<<<blocks4, 256, 0, stream>>>(pm.ego_bf, pm.wfrag, pm.recs,
                pm.type_off_pad, pm.wt_sorted, n_waves);
        k5_agg<<<(N + 31) / 32, 256, 0, stream>>>(pm.ego_bf, pm.wt_sorted,
                pm.head_off, pm.out, N, E);
    }
}